// Round 5
// baseline (197.616 us; speedup 1.0000x reference)
//
#include <hip/hip_runtime.h>

#define SCAN_THREADS 256
#define EPT 8
#define CHUNK (SCAN_THREADS * EPT)   // 2048 elements per scan chunk
#define MAX_CHUNKS 1024              // lookback descriptor slots (8KB)

typedef int   v2i __attribute__((ext_vector_type(2)));
typedef int   v4i __attribute__((ext_vector_type(4)));
typedef float v2f __attribute__((ext_vector_type(2)));
typedef float v4f __attribute__((ext_vector_type(4)));

// Packed lookback descriptor: hi 32 = flag (0=invalid, 1=aggregate, 2=inclusive),
// lo 32 = float bits. Single 64-bit atomic => flag+value travel together.
__device__ __forceinline__ unsigned long long lb_pack(int flag, float v) {
    return ((unsigned long long)(unsigned)flag << 32) |
           (unsigned long long)__float_as_uint(v);
}

// ---------------------------------------------------------------------------
// K1: filtered = residues * sigmoid(attrs @ w + b); scatter +/- into delta.
// tpre u tpost is a permutation of [0,2N) -> every slot written exactly once.
// Block 0 also zeroes the lookback descriptors for k_scan (stream-ordered).
// Streamed inputs nt-loaded so delta's scattered stores stay L2-resident.
__global__ void k1_filter_scatter(const float* __restrict__ attrs,
                                  const float* __restrict__ weight,
                                  const float* __restrict__ bias,
                                  const float* __restrict__ residues,
                                  const int* __restrict__ tpre,
                                  const int* __restrict__ tpost,
                                  float* __restrict__ delta,
                                  unsigned long long* lb,
                                  int N, int numChunks) {
    if (lb && blockIdx.x == 0) {
        for (int i = threadIdx.x; i < numChunks; i += blockDim.x) lb[i] = 0ull;
    }
    int u0 = (blockIdx.x * blockDim.x + threadIdx.x) * 2;
    v4f w0 = *(const v4f*)weight;
    v4f w1 = *(const v4f*)(weight + 4);
    float b = bias[0];
    if (u0 + 2 <= N) {
        v2f rr = __builtin_nontemporal_load((const v2f*)(residues + u0));
        v2i pr = __builtin_nontemporal_load((const v2i*)(tpre + u0));
        v2i po = __builtin_nontemporal_load((const v2i*)(tpost + u0));
        v4f a00 = __builtin_nontemporal_load((const v4f*)(attrs + (size_t)u0 * 8));
        v4f a01 = __builtin_nontemporal_load((const v4f*)(attrs + (size_t)u0 * 8 + 4));
        v4f a10 = __builtin_nontemporal_load((const v4f*)(attrs + (size_t)u0 * 8 + 8));
        v4f a11 = __builtin_nontemporal_load((const v4f*)(attrs + (size_t)u0 * 8 + 12));
        float l0 = a00.x*w0.x + a00.y*w0.y + a00.z*w0.z + a00.w*w0.w +
                   a01.x*w1.x + a01.y*w1.y + a01.z*w1.z + a01.w*w1.w + b;
        float l1 = a10.x*w0.x + a10.y*w0.y + a10.z*w0.z + a10.w*w0.w +
                   a11.x*w1.x + a11.y*w1.y + a11.z*w1.z + a11.w*w1.w + b;
        float f0 = rr.x / (1.0f + __expf(-l0));
        float f1 = rr.y / (1.0f + __expf(-l1));
        delta[pr.x] =  f0; delta[pr.y] =  f1;
        delta[po.x] = -f0; delta[po.y] = -f1;
    } else {
        for (int u = u0; u < N; ++u) {
            float logit = b;
            #pragma unroll
            for (int k = 0; k < 8; ++k) logit += attrs[(size_t)u * 8 + k] * weight[k];
            float f = residues[u] / (1.0f + __expf(-logit));
            delta[tpre[u]]  =  f;
            delta[tpost[u]] = -f;
        }
    }
}

// ---------------------------------------------------------------------------
// K_SCAN: single-pass inclusive scan with decoupled lookback (replaces k2+k4:
// one kernel boundary and one 4MB delta re-read removed; no contended atomics).
// All 489 blocks co-resident (4 waves/block << 8192 slots) => spin is safe.
__global__ __launch_bounds__(SCAN_THREADS)
void k_scan_lookback(float* __restrict__ data,
                     unsigned long long* __restrict__ lb, int T) {
    __shared__ float wavesums[SCAN_THREADS / 64];
    __shared__ float s_excl;
    const int c = blockIdx.x;
    const int tid = threadIdx.x, lane = tid & 63, wid = tid >> 6;

    int base = c * CHUNK + tid * EPT;
    float v[EPT];
    bool full = (base + EPT <= T);
    if (full) {
        v4f v0 = *(const v4f*)(data + base);
        v4f v1 = *(const v4f*)(data + base + 4);
        v[0]=v0.x; v[1]=v0.y; v[2]=v0.z; v[3]=v0.w;
        v[4]=v1.x; v[5]=v1.y; v[6]=v1.z; v[7]=v1.w;
    } else {
        for (int i = 0; i < EPT; ++i)
            v[i] = (base + i < T) ? data[base + i] : 0.0f;
    }
    float run = 0.0f;
    #pragma unroll
    for (int i = 0; i < EPT; ++i) { run += v[i]; v[i] = run; }
    float tot = run;
    float x = tot;
    #pragma unroll
    for (int d = 1; d < 64; d <<= 1) {
        float y = __shfl_up(x, d, 64);
        if (lane >= d) x += y;
    }
    if (lane == 63) wavesums[wid] = x;
    __syncthreads();
    float blockAgg = wavesums[0] + wavesums[1] + wavesums[2] + wavesums[3];

    // Publish this chunk's descriptor.
    if (tid == 0) {
        __hip_atomic_store(&lb[c], lb_pack(c == 0 ? 2 : 1, blockAgg),
                           __ATOMIC_RELEASE, __HIP_MEMORY_SCOPE_AGENT);
        if (c == 0) s_excl = 0.0f;
    }

    // Wave-parallel lookback: 64 predecessors per dependent L2 round-trip.
    if (c > 0 && wid == 0) {
        float running = 0.0f;
        int pos = c - 1;
        while (true) {
            int idx = pos - lane;                  // lane 0 = nearest predecessor
            int flag; float val;
            if (idx >= 0) {
                unsigned long long w = __hip_atomic_load(
                    &lb[idx], __ATOMIC_ACQUIRE, __HIP_MEMORY_SCOPE_AGENT);
                flag = (int)(w >> 32);
                val  = __uint_as_float((unsigned)w);
            } else { flag = 2; val = 0.0f; }       // before chunk 0: inclusive 0
            unsigned long long inclmask = __ballot(flag == 2);
            unsigned long long invmask  = __ballot(flag == 0);
            if (inclmask != 0) {
                int lstar = __ffsll((long long)inclmask) - 1;   // nearest inclusive
                unsigned long long below =
                    (lstar >= 63) ? 0x7FFFFFFFFFFFFFFFull : ((1ull << lstar) - 1ull);
                if ((invmask & below) == 0) {
                    float contrib = (lane <= lstar) ? val : 0.0f;  // aggs below + incl
                    #pragma unroll
                    for (int d = 32; d > 0; d >>= 1)
                        contrib += __shfl_down(contrib, d, 64);
                    running += __shfl(contrib, 0, 64);
                    break;
                }
            } else if (invmask == 0) {             // full window of aggregates
                float contrib = val;
                #pragma unroll
                for (int d = 32; d > 0; d >>= 1)
                    contrib += __shfl_down(contrib, d, 64);
                running += __shfl(contrib, 0, 64);
                pos -= 64;
                continue;
            }
            __builtin_amdgcn_s_sleep(1);           // brief re-poll backoff
        }
        if (lane == 0) {
            s_excl = running;
            __hip_atomic_store(&lb[c], lb_pack(2, running + blockAgg),
                               __ATOMIC_RELEASE, __HIP_MEMORY_SCOPE_AGENT);
        }
    }
    __syncthreads();

    float woff = 0.0f;
    #pragma unroll
    for (int i = 0; i < SCAN_THREADS / 64; ++i)
        if (i < wid) woff += wavesums[i];
    float add = (x - tot) + woff + s_excl;
    if (full) {
        v4f o0 = { v[0]+add, v[1]+add, v[2]+add, v[3]+add };
        v4f o1 = { v[4]+add, v[5]+add, v[6]+add, v[7]+add };
        *(v4f*)(data + base)     = o0;
        *(v4f*)(data + base + 4) = o1;
    } else {
        for (int i = 0; i < EPT; ++i)
            if (base + i < T) data[base + i] = v[i] + add;
    }
}

// ---------------------------------------------------------------------------
// Legacy two-kernel scan (fallback tiers only).
__global__ void k2_partials(const float* __restrict__ delta,
                            float* __restrict__ partials, int T) {
    __shared__ float sdata[SCAN_THREADS / 64];
    int base = blockIdx.x * CHUNK + threadIdx.x * EPT;
    float s = 0.0f;
    if (base + EPT <= T) {
        v4f v0 = *(const v4f*)(delta + base);
        v4f v1 = *(const v4f*)(delta + base + 4);
        s = v0.x + v0.y + v0.z + v0.w + v1.x + v1.y + v1.z + v1.w;
    } else {
        for (int i = 0; i < EPT; ++i)
            if (base + i < T) s += delta[base + i];
    }
    #pragma unroll
    for (int d = 32; d > 0; d >>= 1) s += __shfl_down(s, d, 64);
    int lane = threadIdx.x & 63, wid = threadIdx.x >> 6;
    if (lane == 0) sdata[wid] = s;
    __syncthreads();
    if (threadIdx.x == 0)
        partials[blockIdx.x] = sdata[0] + sdata[1] + sdata[2] + sdata[3];
}

__global__ void k4_scan_chunks(float* __restrict__ data,
                               const float* __restrict__ partials, int T) {
    __shared__ float wavesums[SCAN_THREADS / 64];
    __shared__ float redsum[SCAN_THREADS / 64];
    int lane = threadIdx.x & 63, wid = threadIdx.x >> 6;
    float c = 0.0f;
    for (int i = threadIdx.x; i < blockIdx.x; i += SCAN_THREADS)
        c += partials[i];
    #pragma unroll
    for (int d = 32; d > 0; d >>= 1) c += __shfl_down(c, d, 64);
    if (lane == 0) redsum[wid] = c;

    int base = blockIdx.x * CHUNK + threadIdx.x * EPT;
    float v[EPT];
    bool full = (base + EPT <= T);
    if (full) {
        v4f v0 = *(const v4f*)(data + base);
        v4f v1 = *(const v4f*)(data + base + 4);
        v[0]=v0.x; v[1]=v0.y; v[2]=v0.z; v[3]=v0.w;
        v[4]=v1.x; v[5]=v1.y; v[6]=v1.z; v[7]=v1.w;
    } else {
        for (int i = 0; i < EPT; ++i)
            v[i] = (base + i < T) ? data[base + i] : 0.0f;
    }
    float run = 0.0f;
    #pragma unroll
    for (int i = 0; i < EPT; ++i) { run += v[i]; v[i] = run; }
    float tot = run;
    float x = tot;
    #pragma unroll
    for (int d = 1; d < 64; d <<= 1) {
        float y = __shfl_up(x, d, 64);
        if (lane >= d) x += y;
    }
    if (lane == 63) wavesums[wid] = x;
    __syncthreads();
    float woff = 0.0f, offset = redsum[0] + redsum[1] + redsum[2] + redsum[3];
    #pragma unroll
    for (int i = 0; i < SCAN_THREADS / 64; ++i)
        if (i < wid) woff += wavesums[i];
    float add = (x - tot) + woff + offset;
    if (full) {
        v4f o0 = { v[0]+add, v[1]+add, v[2]+add, v[3]+add };
        v4f o1 = { v[4]+add, v[5]+add, v[6]+add, v[7]+add };
        *(v4f*)(data + base)     = o0;
        *(v4f*)(data + base + 4) = o1;
    } else {
        for (int i = 0; i < EPT; ++i)
            if (base + i < T) data[base + i] = v[i] + add;
    }
}

// ---------------------------------------------------------------------------
// K5: vnode[u] = ycum[tpre[u]]; 4 nodes/thread, nt index loads.
// vnode store stays PLAIN so it lands in L2 for k6's gathers.
__global__ void k5_node_values(const float* __restrict__ ycum,
                               const int* __restrict__ tpre,
                               float* __restrict__ vnode, int N) {
    int u0 = (blockIdx.x * blockDim.x + threadIdx.x) * 4;
    if (u0 + 4 <= N) {
        v4i t = __builtin_nontemporal_load((const v4i*)(tpre + u0));
        v4f y = { ycum[t.x], ycum[t.y], ycum[t.z], ycum[t.w] };
        *(v4f*)(vnode + u0) = y;
    } else {
        for (int u = u0; u < N; ++u) vnode[u] = ycum[tpre[u]];
    }
}

// ---------------------------------------------------------------------------
// K6: per-pixel gather, 8 px/thread. nt LOADS on the nop stream only; out
// stores stay PLAIN (round-4 lesson: nt stores fragment write-combining,
// WRITE_SIZE 37.8 -> 62.4 MB). vnode gathers plain-cached.
__global__ void k6_gather(const float* __restrict__ vnode,
                          const int* __restrict__ nop,
                          float* __restrict__ out, int P) {
    int i = (blockIdx.x * blockDim.x + threadIdx.x) * 8;
    if (i + 8 <= P) {
        v4i n0 = __builtin_nontemporal_load((const v4i*)(nop + i));
        v4i n1 = __builtin_nontemporal_load((const v4i*)(nop + i + 4));
        v4f o0 = { vnode[n0.x], vnode[n0.y], vnode[n0.z], vnode[n0.w] };
        v4f o1 = { vnode[n1.x], vnode[n1.y], vnode[n1.z], vnode[n1.w] };
        *(v4f*)(out + i)     = o0;
        *(v4f*)(out + i + 4) = o1;
    } else {
        for (; i < P; ++i) out[i] = vnode[nop[i]];
    }
}

// K6 fallback: direct double gather (tiny-ws tier only).
__global__ void k6_direct(const float* __restrict__ ycum,
                          const int* __restrict__ tpre,
                          const int* __restrict__ nop,
                          float* __restrict__ out, int P) {
    int i = (blockIdx.x * blockDim.x + threadIdx.x) * 4;
    if (i + 4 <= P) {
        v4i n = *(const v4i*)(nop + i);
        v4f o = { ycum[tpre[n.x]], ycum[tpre[n.y]], ycum[tpre[n.z]], ycum[tpre[n.w]] };
        *(v4f*)(out + i) = o;
    } else {
        for (; i < P; ++i) out[i] = ycum[tpre[nop[i]]];
    }
}

extern "C" void kernel_launch(void* const* d_in, const int* in_sizes, int n_in,
                              void* d_out, int out_size, void* d_ws, size_t ws_size,
                              hipStream_t stream) {
    const float* weight   = (const float*)d_in[0];
    const float* bias     = (const float*)d_in[1];
    const float* residues = (const float*)d_in[2];
    const float* attrs    = (const float*)d_in[3];
    const int*   tpre     = (const int*)d_in[4];
    const int*   tpost    = (const int*)d_in[5];
    const int*   nop      = (const int*)d_in[6];
    float* out = (float*)d_out;

    const int N = in_sizes[2];        // 500,000
    const int T = 2 * N;              // 1,000,000
    const int P = out_size;           // 8,388,608
    const int numChunks = (T + CHUNK - 1) / CHUNK;   // 489

    size_t needFull = (size_t)(T + N) * sizeof(float) + MAX_CHUNKS * 8 + 256;
    size_t needMid  = (size_t)N * sizeof(float) + MAX_CHUNKS * 8 + 256;

    float* delta;
    float* vnode = nullptr;
    unsigned long long* lb;
    bool useVnode = true;

    if (ws_size >= needFull) {
        delta = (float*)d_ws;
        vnode = delta + T;
        lb    = (unsigned long long*)(vnode + N);   // 8-aligned: T,N even
    } else if (ws_size >= needMid) {
        delta = out;                  // dead until k6 rewrites it fully
        vnode = (float*)d_ws;
        lb    = (unsigned long long*)(vnode + N);
    } else {
        delta = out;
        lb    = (unsigned long long*)d_ws;          // reused as float* partials
        useVnode = false;
    }

    const int k1Blocks = (N / 2 + 255) / 256;
    bool lookback = (numChunks <= MAX_CHUNKS) && useVnode;

    k1_filter_scatter<<<k1Blocks, 256, 0, stream>>>(
        attrs, weight, bias, residues, tpre, tpost, delta,
        lookback ? lb : nullptr, N, numChunks);

    if (lookback) {
        k_scan_lookback<<<numChunks, SCAN_THREADS, 0, stream>>>(delta, lb, T);
    } else {
        float* partials = (float*)lb;
        k2_partials<<<numChunks, SCAN_THREADS, 0, stream>>>(delta, partials, T);
        k4_scan_chunks<<<numChunks, SCAN_THREADS, 0, stream>>>(delta, partials, T);
    }

    if (useVnode) {
        k5_node_values<<<(N / 4 + 255) / 256, 256, 0, stream>>>(delta, tpre, vnode, N);
        int gatherBlocks = (P / 8 + 255) / 256;
        k6_gather<<<gatherBlocks, 256, 0, stream>>>(vnode, nop, out, P);
    } else {
        int gatherBlocks = (P / 4 + 255) / 256;
        k6_direct<<<gatherBlocks, 256, 0, stream>>>(delta, tpre, nop, out, P);
    }
}